// Round 9
// baseline (11921.548 us; speedup 1.0000x reference)
//
#include <hip/hip_runtime.h>

#define N_PTS 16384
#define M_PTS 4096
#define D_INF 64
#define D_OUTF 128
#define KNN 16
#define DF 67   // 3 + 64

// ---------------- squared norms of p, numpy op order ----------------
__global__ __launch_bounds__(256) void sp_kernel(const float* __restrict__ p,
                                                 float* __restrict__ spn) {
  int j = blockIdx.x * 256 + threadIdx.x;
  float a = p[3 * j], b = p[3 * j + 1], c = p[3 * j + 2];
  spn[j] = __fadd_rn(__fadd_rn(__fmul_rn(a, a), __fmul_rn(b, b)), __fmul_rn(c, c));
}

// ---------------- FPS: bucketed skip (QuickFPS-style), bit-exact ----------------
// Brute force is pinned at 1.8-2.9 us/iter (R0-R7). Skip work instead: points
// bucketed on an 8^3 grid, permuted bucket-contiguous into global
// float4(x,y,z,orig_idx) (L2-hot); dd + per-bucket {bbox, max_dd, argmax
// (min-orig-idx), argmax pos} live in LDS (~92 KB). Per iter a bucket is
// skipped iff dist2(last, bbox) >= its stored max_dd. Float-exact safety:
// same op order ((dx*dx+dy*dy)+dz*dz), fsub-based bbox clamps, rn monotonicity
// => every member's fresh d >= bboxd >= max_dd >= dd => min(dd,d) unchanged,
// so skipped buckets' candidates stay bit-exact. Updated buckets recompute dd
// with the exact reference formula. Global winner = (max val, min orig idx)
// over per-bucket candidates == jnp.argmax first-occurrence. vs R8 (which
// died on a harness exception): dynamic LDS-atomic work queue removed (static
// strided bucket assignment), 1000->512 cells (1 bbox test + 1 reduce cell
// per thread), less LDS. No spin loops anywhere; all barriers uniform.
#define FPS_T 512
#define NW (FPS_T / 64)
#define GRD 8
#define CELLS 512   // GRD^3

__global__ __launch_bounds__(FPS_T) void fps_kernel(const float* __restrict__ p,
                                                    int* __restrict__ sidx,
                                                    float* __restrict__ np_out,
                                                    float4* __restrict__ ppk) {
  const int t = threadIdx.x;
  const int lane = t & 63;
  const int w = t >> 6;

  __shared__ float s_dd[N_PTS];        // 64 KB
  __shared__ float s_blo[3][CELLS];    // 6 KB
  __shared__ float s_bhi[3][CELLS];    // 6 KB
  __shared__ float s_bmax[CELLS];      // 2 KB
  __shared__ int   s_bidx[CELLS];      // 2 KB
  __shared__ int   s_bpos[CELLS];      // 2 KB
  __shared__ int   s_start[CELLS];     // 2 KB
  __shared__ int   s_cnt[CELLS];       // 2 KB
  __shared__ int   s_aff[CELLS];       // 2 KB
  __shared__ int   s_ofs[CELLS];       // 2 KB
  __shared__ float s_mm[NW][8];
  __shared__ int   s_wsum[NW];
  __shared__ float4 s_red[NW];
  __shared__ int   s_naff;

  // ---- prologue 1: global coord min/max (exact fminf/fmaxf) ----
  float mlx = INFINITY, mly = INFINITY, mlz = INFINITY;
  float mhx = -INFINITY, mhy = -INFINITY, mhz = -INFINITY;
  for (int k = 0; k < N_PTS / FPS_T; ++k) {
    int j = t + (k << 9);
    float a = p[3 * j], b = p[3 * j + 1], c = p[3 * j + 2];
    mlx = fminf(mlx, a); mly = fminf(mly, b); mlz = fminf(mlz, c);
    mhx = fmaxf(mhx, a); mhy = fmaxf(mhy, b); mhz = fmaxf(mhz, c);
  }
#pragma unroll
  for (int off = 32; off >= 1; off >>= 1) {
    mlx = fminf(mlx, __shfl_xor(mlx, off));
    mly = fminf(mly, __shfl_xor(mly, off));
    mlz = fminf(mlz, __shfl_xor(mlz, off));
    mhx = fmaxf(mhx, __shfl_xor(mhx, off));
    mhy = fmaxf(mhy, __shfl_xor(mhy, off));
    mhz = fmaxf(mhz, __shfl_xor(mhz, off));
  }
  if (lane == 0) {
    s_mm[w][0] = mlx; s_mm[w][1] = mly; s_mm[w][2] = mlz;
    s_mm[w][3] = mhx; s_mm[w][4] = mhy; s_mm[w][5] = mhz;
  }
  __syncthreads();
  float glox = s_mm[0][0], gloy = s_mm[0][1], gloz = s_mm[0][2];
  float ghix = s_mm[0][3], ghiy = s_mm[0][4], ghiz = s_mm[0][5];
#pragma unroll
  for (int w2 = 1; w2 < NW; ++w2) {
    glox = fminf(glox, s_mm[w2][0]); gloy = fminf(gloy, s_mm[w2][1]);
    gloz = fminf(gloz, s_mm[w2][2]);
    ghix = fmaxf(ghix, s_mm[w2][3]); ghiy = fmaxf(ghiy, s_mm[w2][4]);
    ghiz = fmaxf(ghiz, s_mm[w2][5]);
  }
  // uniform across threads (same inputs, same op order)
  const float invx = (float)GRD / (ghix - glox);
  const float invy = (float)GRD / (ghiy - gloy);
  const float invz = (float)GRD / (ghiz - gloz);

#define CELL_OF(A, B, C, OUT)                                            \
  do {                                                                   \
    int cx_ = (int)(((A) - glox) * invx);                                \
    int cy_ = (int)(((B) - gloy) * invy);                                \
    int cz_ = (int)(((C) - gloz) * invz);                                \
    cx_ = max(0, min(GRD - 1, cx_));                                     \
    cy_ = max(0, min(GRD - 1, cy_));                                     \
    cz_ = max(0, min(GRD - 1, cz_));                                     \
    OUT = (cx_ * GRD + cy_) * GRD + cz_;                                 \
  } while (0)

  // ---- prologue 2: histogram ----
  s_cnt[t] = 0;
  __syncthreads();
  for (int k = 0; k < N_PTS / FPS_T; ++k) {
    int j = t + (k << 9);
    int cell; CELL_OF(p[3 * j], p[3 * j + 1], p[3 * j + 2], cell);
    atomicAdd(&s_cnt[cell], 1);
  }
  __syncthreads();
  // ---- prologue 3: exclusive scan (one cell per thread) ----
  {
    int c0 = s_cnt[t];
    int inc = c0;
#pragma unroll
    for (int off = 1; off <= 32; off <<= 1) {
      int o = __shfl_up(inc, off);
      if (lane >= off) inc += o;
    }
    if (lane == 63) s_wsum[w] = inc;
    __syncthreads();
    int woff = 0;
    for (int w2 = 0; w2 < w; ++w2) woff += s_wsum[w2];
    int ex = woff + inc - c0;
    s_start[t] = ex;
    s_ofs[t] = ex;
  }
  __syncthreads();
  // ---- prologue 4: scatter bucket-contiguous + dd init ----
  for (int k = 0; k < N_PTS / FPS_T; ++k) {
    int j = t + (k << 9);
    float a = p[3 * j], b = p[3 * j + 1], c = p[3 * j + 2];
    int cell; CELL_OF(a, b, c, cell);
    int pos = atomicAdd(&s_ofs[cell], 1);
    ppk[pos] = make_float4(a, b, c, __int_as_float(j));
    s_dd[pos] = INFINITY;
  }
  __syncthreads();
  // ---- prologue 5: per-bucket bbox (exact member min/max) + candidate init ----
  for (int bkt = w; bkt < CELLS; bkt += NW) {
    int s = s_start[bkt], e = s + s_cnt[bkt];
    float blx = INFINITY, bly = INFINITY, blz = INFINITY;
    float bhx = -INFINITY, bhy = -INFINITY, bhz = -INFINITY;
    for (int j = s + lane; j < e; j += 64) {
      float4 f = ppk[j];
      blx = fminf(blx, f.x); bly = fminf(bly, f.y); blz = fminf(blz, f.z);
      bhx = fmaxf(bhx, f.x); bhy = fmaxf(bhy, f.y); bhz = fmaxf(bhz, f.z);
    }
#pragma unroll
    for (int off = 32; off >= 1; off >>= 1) {
      blx = fminf(blx, __shfl_xor(blx, off));
      bly = fminf(bly, __shfl_xor(bly, off));
      blz = fminf(blz, __shfl_xor(blz, off));
      bhx = fmaxf(bhx, __shfl_xor(bhx, off));
      bhy = fmaxf(bhy, __shfl_xor(bhy, off));
      bhz = fmaxf(bhz, __shfl_xor(bhz, off));
    }
    if (lane == 0) {
      s_blo[0][bkt] = blx; s_blo[1][bkt] = bly; s_blo[2][bkt] = blz;
      s_bhi[0][bkt] = bhx; s_bhi[1][bkt] = bhy; s_bhi[2][bkt] = bhz;
      s_bmax[bkt] = (s_cnt[bkt] > 0) ? INFINITY : -INFINITY;
      s_bidx[bkt] = 0x7FFFFFFF;
      s_bpos[bkt] = 0;
    }
  }
  if (t == 0) {
    s_naff = 0;
    sidx[0] = 0;
    np_out[0] = p[0]; np_out[1] = p[1]; np_out[2] = p[2];
  }
  float lx = p[0], ly = p[1], lz = p[2];
  __syncthreads();

  // ---- main loop ----
  for (int i = 1; i < M_PTS; ++i) {
    // P1: skip test, one cell per thread. Affected iff dist2(last,bbox) < bmax.
    {
      const int bb = t;
      float ax = __fsub_rn(s_blo[0][bb], lx);
      float bx = __fsub_rn(lx, s_bhi[0][bb]);
      float dxb = fmaxf(fmaxf(ax, bx), 0.0f);
      float ay = __fsub_rn(s_blo[1][bb], ly);
      float by = __fsub_rn(ly, s_bhi[1][bb]);
      float dyb = fmaxf(fmaxf(ay, by), 0.0f);
      float az = __fsub_rn(s_blo[2][bb], lz);
      float bz = __fsub_rn(lz, s_bhi[2][bb]);
      float dzb = fmaxf(fmaxf(az, bz), 0.0f);
      float dsq = __fadd_rn(__fadd_rn(__fmul_rn(dxb, dxb), __fmul_rn(dyb, dyb)),
                            __fmul_rn(dzb, dzb));
      if (dsq < s_bmax[bb]) {
        int pos = atomicAdd(&s_naff, 1);
        s_aff[pos] = bb;
      }
    }
    __syncthreads();  // B1
    // P2: update affected buckets, static strided wave assignment
    const int naff = s_naff;
    for (int a = w; a < naff; a += NW) {
      const int bkt = s_aff[a];
      const int s = s_start[bkt], e = s + s_cnt[bkt];
      float v = -INFINITY; int oi = 0x7FFFFFFF, pj = 0;
      for (int j = s + lane; j < e; j += 64) {
        float4 f = ppk[j];
        float dx = __fsub_rn(f.x, lx);
        float dy = __fsub_rn(f.y, ly);
        float dz = __fsub_rn(f.z, lz);
        float d = __fadd_rn(__fadd_rn(__fmul_rn(dx, dx), __fmul_rn(dy, dy)),
                            __fmul_rn(dz, dz));
        float nd = fminf(s_dd[j], d);
        s_dd[j] = nd;
        int o = __float_as_int(f.w);
        bool tk = (nd > v) || (nd == v && o < oi);
        v = tk ? nd : v; oi = tk ? o : oi; pj = tk ? j : pj;
      }
#pragma unroll
      for (int off = 32; off >= 1; off >>= 1) {
        float ov = __shfl_xor(v, off);
        int ooi = __shfl_xor(oi, off);
        int opj = __shfl_xor(pj, off);
        bool tk = (ov > v) || (ov == v && ooi < oi);
        v = tk ? ov : v; oi = tk ? ooi : oi; pj = tk ? opj : pj;
      }
      if (lane == 0) { s_bmax[bkt] = v; s_bidx[bkt] = oi; s_bpos[bkt] = pj; }
    }
    __syncthreads();  // B2
    // P3: global argmax over per-cell candidates (max val, tie -> min orig idx)
    float v = s_bmax[t]; int oi = s_bidx[t], pj = s_bpos[t];
#pragma unroll
    for (int off = 32; off >= 1; off >>= 1) {
      float ov = __shfl_xor(v, off);
      int ooi = __shfl_xor(oi, off);
      int opj = __shfl_xor(pj, off);
      bool tk = (ov > v) || (ov == v && ooi < oi);
      v = tk ? ov : v; oi = tk ? ooi : oi; pj = tk ? opj : pj;
    }
    if (lane == 0) s_red[w] = make_float4(v, __int_as_float(oi), __int_as_float(pj), 0.f);
    if (t == 0) s_naff = 0;  // reset for next iter (B2 separates last read)
    __syncthreads();  // B3
    float4 e0 = s_red[0];
    float gv = e0.x; int goi = __float_as_int(e0.y), gpj = __float_as_int(e0.z);
#pragma unroll
    for (int w2 = 1; w2 < NW; ++w2) {
      float4 e = s_red[w2];
      float ov = e.x; int ooi = __float_as_int(e.y);
      bool tk = (ov > gv) || (ov == gv && ooi < goi);
      gv = tk ? ov : gv; goi = tk ? ooi : goi;
      gpj = tk ? __float_as_int(e.z) : gpj;
    }
    float4 wf = ppk[gpj];  // uniform L2-hot read of winner coords
    lx = wf.x; ly = wf.y; lz = wf.z;
    if (t == 0) {
      sidx[i] = goi;
      np_out[3 * i] = lx; np_out[3 * i + 1] = ly; np_out[3 * i + 2] = lz;
    }
  }
}

// ---------------- kNN + grouping + maxpool features: one wave per query ----
__global__ __launch_bounds__(256) void knn_feat_kernel(const float* __restrict__ p,
                                                       const float* __restrict__ x,
                                                       const float* __restrict__ spn,
                                                       const int* __restrict__ sidx,
                                                       float* __restrict__ feat) {
  __shared__ float cd[4][256];
  __shared__ int ci[4][256];
  __shared__ int cnt[4];
  __shared__ int s_nn[4][KNN];
  const int w = threadIdx.x >> 6;
  const int lane = threadIdx.x & 63;
  const int q = (blockIdx.x << 2) + w;
  const int qi = sidx[q];
  const float qx = p[3 * qi], qy = p[3 * qi + 1], qz = p[3 * qi + 2];
  const float sn = spn[qi];
  if (lane == 0) cnt[w] = 0;
  // Phase A: per-lane min distance over its 256 candidates
  float lmin = INFINITY;
  for (int it = 0; it < N_PTS / 64; ++it) {
    int j = lane + (it << 6);
    float dot = __fmaf_rn(qz, p[3 * j + 2],
                 __fmaf_rn(qy, p[3 * j + 1], __fmul_rn(qx, p[3 * j])));
    float d2 = __fsub_rn(__fadd_rn(sn, spn[j]), __fmul_rn(2.0f, dot));
    lmin = fminf(lmin, d2);
  }
  // tau = 16th smallest of 64 lane minima (valid upper bound on 16th NN dist)
  float mv = lmin;
  float tau = INFINITY;
#pragma unroll
  for (int r = 0; r < KNN; ++r) {
    float rmin = mv;
#pragma unroll
    for (int off = 32; off >= 1; off >>= 1) rmin = fminf(rmin, __shfl_xor(rmin, off));
    tau = rmin;
    unsigned long long msk = __ballot(mv == rmin);
    if (lane == (int)(__ffsll(msk) - 1)) mv = INFINITY;
  }
  __syncthreads();
  // Phase B: compact all candidates with d2 <= tau (expected ~18-40)
  for (int it = 0; it < N_PTS / 64; ++it) {
    int j = lane + (it << 6);
    float dot = __fmaf_rn(qz, p[3 * j + 2],
                 __fmaf_rn(qy, p[3 * j + 1], __fmul_rn(qx, p[3 * j])));
    float d2 = __fsub_rn(__fadd_rn(sn, spn[j]), __fmul_rn(2.0f, dot));
    if (d2 <= tau) {
      int pos = atomicAdd(&cnt[w], 1);
      if (pos < 256) { cd[w][pos] = d2; ci[w][pos] = j; }
    }
  }
  __syncthreads();
  // Phase C: extract 16 smallest by (value, index) — stable top_k semantics
  int C = min(cnt[w], 256);
  float vv[4]; int ii[4];
#pragma unroll
  for (int s = 0; s < 4; ++s) {
    int pos = lane + (s << 6);
    bool ok = pos < C;
    vv[s] = ok ? cd[w][pos] : INFINITY;
    ii[s] = ok ? ci[w][pos] : 0x7FFFFFFF;
  }
#pragma unroll
  for (int r = 0; r < KNN; ++r) {
    float bv = vv[0]; int bi = ii[0]; int bs = 0;
#pragma unroll
    for (int s = 1; s < 4; ++s) {
      bool tk = (vv[s] < bv) || (vv[s] == bv && ii[s] < bi);
      bv = tk ? vv[s] : bv; bi = tk ? ii[s] : bi; bs = tk ? s : bs;
    }
    float rv = bv; int ri = bi;
#pragma unroll
    for (int off = 32; off >= 1; off >>= 1) {
      float ov = __shfl_xor(rv, off); int oi = __shfl_xor(ri, off);
      bool tk = (ov < rv) || (ov == rv && oi < ri);
      rv = tk ? ov : rv; ri = tk ? oi : ri;
    }
    if (bi == ri) {  // my local-best slot won: retire it
#pragma unroll
      for (int s = 0; s < 4; ++s) if (s == bs) vv[s] = INFINITY;
    }
    if (lane == 0) s_nn[w][r] = ri;
  }
  __syncthreads();
  // Phase D: relative coords, norm scaling, maxpool
  float ax = -INFINITY, ay = -INFINITY, az = -INFINITY, nr = -INFINITY;
  if (lane < KNN) {
    int jn = s_nn[w][lane];
    ax = __fsub_rn(p[3 * jn], qx);
    ay = __fsub_rn(p[3 * jn + 1], qy);
    az = __fsub_rn(p[3 * jn + 2], qz);
    nr = sqrtf(__fadd_rn(__fadd_rn(__fmul_rn(ax, ax), __fmul_rn(ay, ay)),
                         __fmul_rn(az, az)));
  }
  float mnr = nr, mx = ax, my = ay, mz = az;
#pragma unroll
  for (int off = 32; off >= 1; off >>= 1) {
    mnr = fmaxf(mnr, __shfl_xor(mnr, off));
    mx = fmaxf(mx, __shfl_xor(mx, off));
    my = fmaxf(my, __shfl_xor(my, off));
    mz = fmaxf(mz, __shfl_xor(mz, off));
  }
  if (lane == 0) {
    // max over k commutes exactly with the (monotone) division
    float sden = __fadd_rn(mnr, 1e-8f);
    feat[q * DF + 0] = mx / sden;
    feat[q * DF + 1] = my / sden;
    feat[q * DF + 2] = mz / sden;
  }
  float fm = -INFINITY;
#pragma unroll
  for (int k = 0; k < KNN; ++k) {
    int jn = s_nn[w][k];
    fm = fmaxf(fm, x[(jn << 6) + lane]);
  }
  feat[q * DF + 3 + lane] = fm;
}

// ---------------- MLP: h = feat @ W + b ----------------
__global__ __launch_bounds__(128) void mlp_kernel(const float* __restrict__ feat,
                                                  const float* __restrict__ W,
                                                  const float* __restrict__ b,
                                                  float* __restrict__ h) {
  int mrow = blockIdx.x;
  int o = threadIdx.x;
  const float* fr = feat + mrow * DF;
  float acc = b[o];
#pragma unroll
  for (int k = 0; k < DF; ++k) acc = __fmaf_rn(fr[k], W[k * D_OUTF + o], acc);
  h[mrow * D_OUTF + o] = acc;
}

// ---------------- BN column stats (training mode) ----------------
__global__ __launch_bounds__(256) void stats_kernel(const float* __restrict__ h,
                                                    const float* __restrict__ gamma,
                                                    const float* __restrict__ beta,
                                                    float* __restrict__ scsh) {
  int o = blockIdx.x;
  int t = threadIdx.x;
  float s = 0.f, s2 = 0.f;
  for (int mrow = t; mrow < M_PTS; mrow += 256) {
    float v = h[mrow * D_OUTF + o];
    s += v;
    s2 = __fmaf_rn(v, v, s2);
  }
#pragma unroll
  for (int off = 32; off >= 1; off >>= 1) {
    s += __shfl_xor(s, off);
    s2 += __shfl_xor(s2, off);
  }
  __shared__ float as1[4], as2[4];
  if ((t & 63) == 0) { as1[t >> 6] = s; as2[t >> 6] = s2; }
  __syncthreads();
  if (t == 0) {
    float ts = ((as1[0] + as1[1]) + as1[2]) + as1[3];
    float ts2 = ((as2[0] + as2[1]) + as2[2]) + as2[3];
    float mean = ts / (float)M_PTS;
    float var = ts2 / (float)M_PTS - mean * mean;
    var = fmaxf(var, 0.f);
    float sc = gamma[o] / sqrtf(var + 1e-5f);
    scsh[o] = sc;
    scsh[D_OUTF + o] = beta[o] - mean * sc;
  }
}

// ---------------- BN apply + ReLU + n_o ----------------
__global__ __launch_bounds__(256) void bn_kernel(const float* __restrict__ h,
                                                 const float* __restrict__ scsh,
                                                 float* __restrict__ out) {
  int idx = blockIdx.x * 256 + threadIdx.x;
  int o = idx & (D_OUTF - 1);
  float v = __fmaf_rn(h[idx], scsh[o], scsh[D_OUTF + o]);
  out[M_PTS * 3 + idx] = fmaxf(v, 0.f);
  if (idx == 0) out[M_PTS * 3 + M_PTS * D_OUTF] = 4096.0f;  // n_o
}

extern "C" void kernel_launch(void* const* d_in, const int* in_sizes, int n_in,
                              void* d_out, int out_size, void* d_ws, size_t ws_size,
                              hipStream_t stream) {
  const float* p     = (const float*)d_in[0];
  const float* x     = (const float*)d_in[1];
  // d_in[2] = o (offsets) — unused, single cloud
  const float* W     = (const float*)d_in[3];
  const float* b     = (const float*)d_in[4];
  const float* gamma = (const float*)d_in[5];
  const float* beta  = (const float*)d_in[6];
  float* out = (float*)d_out;

  float* wsf  = (float*)d_ws;
  int*   sidx = (int*)d_ws;                    // [4096]
  float* spn  = wsf + 4096;                    // [16384]
  float* feat = spn + N_PTS;                   // [4096 * 67]
  float* h    = feat + M_PTS * DF;             // [4096 * 128]
  float* scsh = h + M_PTS * D_OUTF;            // [256]

  // fps scratch: permuted float4(x,y,z,orig_idx) — overlaps h (first written
  // after fps completes, by mlp_kernel). 16384*4 floats <= h's 524288 floats.
  float4* ppk = (float4*)h;

  sp_kernel<<<N_PTS / 256, 256, 0, stream>>>(p, spn);
  fps_kernel<<<1, FPS_T, 0, stream>>>(p, sidx, out, ppk);
  knn_feat_kernel<<<M_PTS / 4, 256, 0, stream>>>(p, x, spn, sidx, feat);
  mlp_kernel<<<M_PTS, D_OUTF, 0, stream>>>(feat, W, b, h);
  stats_kernel<<<D_OUTF, 256, 0, stream>>>(h, gamma, beta, scsh);
  bn_kernel<<<(M_PTS * D_OUTF) / 256, 256, 0, stream>>>(h, scsh, out);
}